// Round 6
// baseline (326.126 us; speedup 1.0000x reference)
//
#include <hip/hip_runtime.h>
#include <hip/hip_bf16.h>

typedef __attribute__((ext_vector_type(8))) short   bf16x8;
typedef __attribute__((ext_vector_type(4))) float   f32x4;
typedef unsigned short u16;

#define NTOK 64
#define CEMB 192
#define NH   6
#define ROWB 384   // row bytes for [64][192] bf16 tiles
#define VROWB 128  // row bytes for vhT [192][64] bf16

__device__ __forceinline__ u16 f2b(float f) {
  unsigned u = __float_as_uint(f);
  unsigned r = (u + 0x7fffu + ((u >> 16) & 1u)) >> 16;  // RNE
  return (u16)r;
}

// hardware packed f32->bf16
__device__ __forceinline__ unsigned cvtpk(float lo, float hi) {
  unsigned r;
  asm("v_cvt_pk_bf16_f32 %0, %1, %2" : "=v"(r) : "v"(lo), "v"(hi));
  return r;
}

__device__ __forceinline__ int swz(int row, int colbyte) {
  return colbyte ^ ((((row >> 3) ^ row) & 7) << 4);
}

// ---------------- prep: pack W^T (bf16) + gather rel_bias ----------------
__global__ void prep_kernel(const float* __restrict__ Wq, const float* __restrict__ Wk,
                            const float* __restrict__ Wv, const float* __restrict__ Wp,
                            const float* __restrict__ btab, const int* __restrict__ ridx,
                            u16* __restrict__ WT, float* __restrict__ rb) {
  int idx = blockIdx.x * 256 + threadIdx.x;
  if (idx < 4 * 36864) {
    int m = idx / 36864;
    int e = idx - m * 36864;
    int n = e / CEMB;
    int k = e - n * CEMB;
    const float* W = (m == 0) ? Wq : (m == 1) ? Wk : (m == 2) ? Wv : Wp;
    WT[idx] = f2b(W[k * CEMB + n]);          // WT[m][n][k] = W[k][n]
  } else {
    int i2 = idx - 4 * 36864;
    if (i2 < NH * 4096) {
      int h = i2 >> 12;
      int ij = i2 & 4095;
      rb[i2] = btab[ridx[ij] * NH + h];      // rb[h][i][j]
    }
  }
}

// ---------------- K1: QKV projection, one (matrix, window) per block ----------------
// Linear bf16 outputs (coalesced dwordx4 stores via LDS transpose):
//   qh [64][192] -> x[b] bytes      0..24576
//   kh [64][192] -> x[b] bytes  24576..49152
//   vhT[192][64] -> attn[b] bytes 65536..90112 (h4/h5 slots)
__global__ __launch_bounds__(256, 6)
void proj_kernel(const float* __restrict__ qg, const float* __restrict__ kg,
                 const float* __restrict__ vg,
                 const float* __restrict__ bq, const float* __restrict__ bk,
                 const float* __restrict__ bv,
                 const u16* __restrict__ WT,
                 float* __restrict__ xout, float* __restrict__ attn_out) {
  __shared__ __align__(16) char sT[24576];
  const int tid  = threadIdx.x;
  const int wave = tid >> 6;
  const int lane = tid & 63;
  const int l15  = lane & 15;
  const int lhi  = lane >> 4;
  const int m = blockIdx.x / 2048;        // 0=q 1=k 2=v
  const int b = blockIdx.x - m * 2048;

  const float* src  = (m == 0 ? qg : m == 1 ? kg : vg) + (size_t)b * NTOK * CEMB;
  const float* bias = (m == 0 ? bq : m == 1 ? bk : bv);

  // stage raw tile -> bf16 LDS (swizzled)
  #pragma unroll
  for (int it = 0; it < 12; ++it) {
    int fi  = it * 256 + tid;              // float4 idx 0..3071
    int row = fi / 48;
    int ce  = (fi - row * 48) * 4;
    const float4 v4 = reinterpret_cast<const float4*>(src)[fi];
    uint2 w;
    w.x = cvtpk(v4.x, v4.y);
    w.y = cvtpk(v4.z, v4.w);
    *reinterpret_cast<uint2*>(sT + row * ROWB + swz(row, ce * 2)) = w;
  }
  __syncthreads();

  // 12 col-strips over 4 waves, 3 per wave
  f32x4 acc[3][4];
  #pragma unroll
  for (int si = 0; si < 3; ++si) {
    int ct = wave + si * 4;
    const u16* Wt = WT + m * 36864 + (ct * 16 + l15) * CEMB + lhi * 8;
    #pragma unroll
    for (int rt = 0; rt < 4; ++rt) { f32x4 z = {0.f,0.f,0.f,0.f}; acc[si][rt] = z; }
    #pragma unroll
    for (int ks = 0; ks < 6; ++ks) {
      bf16x8 bw = *reinterpret_cast<const bf16x8*>(Wt + ks * 32);
      #pragma unroll
      for (int rt = 0; rt < 4; ++rt) {
        int row = rt * 16 + l15;
        bf16x8 ax = *reinterpret_cast<const bf16x8*>(sT + row * ROWB + swz(row, ks * 64 + lhi * 16));
        acc[si][rt] = __builtin_amdgcn_mfma_f32_16x16x32_bf16(ax, bw, acc[si][rt], 0, 0, 0);
      }
    }
  }
  __syncthreads();   // staging reads done; sT becomes output-transpose buffer

  const float scale = (m == 0) ? 0.17677669529663687f : 1.0f;
  #pragma unroll
  for (int si = 0; si < 3; ++si) {
    int ct = wave + si * 4;
    int c  = ct * 16 + l15;
    float bval = bias[c];
    if (m == 2) {
      #pragma unroll
      for (int rt = 0; rt < 4; ++rt) {
        int t0 = rt * 16 + lhi * 4;
        uint2 w;
        w.x = cvtpk(acc[si][rt][0] + bval, acc[si][rt][1] + bval);
        w.y = cvtpk(acc[si][rt][2] + bval, acc[si][rt][3] + bval);
        *reinterpret_cast<uint2*>(sT + c * VROWB + swz(c, t0 * 2)) = w;
      }
    } else {
      #pragma unroll
      for (int rt = 0; rt < 4; ++rt)
        #pragma unroll
        for (int r = 0; r < 4; ++r) {
          int row = rt * 16 + lhi * 4 + r;
          *reinterpret_cast<u16*>(sT + row * ROWB + swz(row, c * 2)) = f2b((acc[si][rt][r] + bval) * scale);
        }
    }
  }
  __syncthreads();

  // coalesced 16B store of the 24KB tile to linear global
  u16* xq = (u16*)(xout + (size_t)b * 12288);
  u16* vt = (u16*)(attn_out + (size_t)b * 24576 + 16384);
  u16* dst = (m == 0) ? xq : (m == 1) ? xq + 12288 : vt;
  #pragma unroll
  for (int c6 = 0; c6 < 6; ++c6) {
    int g = c6 * 256 + tid;                // 16B chunk id 0..1535
    int off;
    if (m == 2) { int row = g >> 3; off = row * VROWB + swz(row, (g & 7) * 16); }
    else        { int row = g / 24; off = row * ROWB  + swz(row, (g % 24) * 16); }
    reinterpret_cast<float4*>(dst)[g] = *reinterpret_cast<const float4*>(sT + off);
  }
}

// ---------------- K2: attention + out-proj, one window per block ----------------
// LDS: sKH [64][192] swz @0 (24KB), sVT [192][64] swz @24576 (24KB),
//      sX [64][192] swz @49152 (24KB), sP 4x1KB @73728  -> 76KB, 2 blocks/CU
__global__ __launch_bounds__(256, 2)
void attn_kernel(const float* __restrict__ maskg, const float* __restrict__ bp,
                 const u16* __restrict__ WT, const float* __restrict__ rb,
                 float* __restrict__ xout, float* __restrict__ attn_out) {
  __shared__ __align__(16) char smem[77824];
  char* sKH = smem;
  char* sVT = smem + 24576;
  char* sX  = smem + 49152;
  const int tid  = threadIdx.x;
  const int wave = tid >> 6;                   // == rt
  const int lane = tid & 63;
  const int l15  = lane & 15;
  const int lhi  = lane >> 4;
  char* sP = smem + 73728 + wave * 1024;
  const int b  = blockIdx.x;
  const int rt = wave;
  const int irow = rt * 16 + lhi * 4;

  const u16* xq = (const u16*)(xout + (size_t)b * 12288);             // qh [64][192]
  const float4* khG = (const float4*)(xq + 12288);                    // kh linear
  const float4* vtG = (const float4*)(attn_out + (size_t)b * 24576 + 16384); // vhT linear
  const float* maskw = maskg + (size_t)(b & 1023) * 4096;

  // ---- stage kh + vt into LDS (independent coalesced 16B loads) ----
  #pragma unroll
  for (int it = 0; it < 6; ++it) {
    int g = it * 256 + tid;                   // 16B chunk 0..1535
    int kr = g / 24;
    *reinterpret_cast<float4*>(sKH + kr * ROWB + swz(kr, (g % 24) * 16)) = khG[g];
    int vr = g >> 3;
    *reinterpret_cast<float4*>(sVT + vr * VROWB + swz(vr, (g & 7) * 16)) = vtG[g];
  }

  // hoist mask (head-invariant) while staging lands
  const float* mkp = maskw + irow * 64 + l15;
  float mkv[4][4];
  #pragma unroll
  for (int ct = 0; ct < 4; ++ct)
    #pragma unroll
    for (int r = 0; r < 4; ++r)
      mkv[ct][r] = mkp[r * 64 + ct * 16];

  // prefetch first head's q fragment
  bf16x8 aqC = *reinterpret_cast<const bf16x8*>(xq + (rt * 16 + l15) * CEMB + lhi * 8);
  __syncthreads();   // staged kh/vt visible; global kh/vt/qh regions now "consumed"

  #pragma unroll
  for (int h = 0; h < NH; ++h) {
    bf16x8 aqN;
    if (h < NH - 1)
      aqN = *reinterpret_cast<const bf16x8*>(xq + (rt * 16 + l15) * CEMB + (h + 1) * 32 + lhi * 8);

    const float* rbp = rb + h * 4096 + irow * 64 + l15;
    float rbv[4][4];
    #pragma unroll
    for (int ct = 0; ct < 4; ++ct)
      #pragma unroll
      for (int r = 0; r < 4; ++r)
        rbv[ct][r] = rbp[r * 64 + ct * 16];

    // S = qh @ kh^T (K=32), kh frags from LDS
    f32x4 sv[4];
    #pragma unroll
    for (int ct = 0; ct < 4; ++ct) {
      int krow = ct * 16 + l15;
      bf16x8 bkf = *reinterpret_cast<const bf16x8*>(sKH + krow * ROWB + swz(krow, h * 64 + lhi * 16));
      f32x4 z = {0.f, 0.f, 0.f, 0.f};
      sv[ct] = __builtin_amdgcn_mfma_f32_16x16x32_bf16(aqC, bkf, z, 0, 0, 0);
    }

    float lg[4][4];
    #pragma unroll
    for (int ct = 0; ct < 4; ++ct)
      #pragma unroll
      for (int r = 0; r < 4; ++r)
        lg[ct][r] = sv[ct][r] + rbv[ct][r] + mkv[ct][r];

    float pr[4][4];
    #pragma unroll
    for (int r = 0; r < 4; ++r) {
      float mx = fmaxf(fmaxf(lg[0][r], lg[1][r]), fmaxf(lg[2][r], lg[3][r]));
      mx = fmaxf(mx, __shfl_xor(mx, 1));
      mx = fmaxf(mx, __shfl_xor(mx, 2));
      mx = fmaxf(mx, __shfl_xor(mx, 4));
      mx = fmaxf(mx, __shfl_xor(mx, 8));
      float e0 = __expf(lg[0][r] - mx), e1 = __expf(lg[1][r] - mx);
      float e2 = __expf(lg[2][r] - mx), e3 = __expf(lg[3][r] - mx);
      float sum = e0 + e1 + e2 + e3;
      sum += __shfl_xor(sum, 1);
      sum += __shfl_xor(sum, 2);
      sum += __shfl_xor(sum, 4);
      sum += __shfl_xor(sum, 8);
      float inv = 1.0f / sum;
      pr[0][r] = e0 * inv; pr[1][r] = e1 * inv; pr[2][r] = e2 * inv; pr[3][r] = e3 * inv;
    }

    // attn probs to global — streaming, no deferral needed (sources staged)
    float* ap = attn_out + (((size_t)b * NH + h) * NTOK + irow) * NTOK;
    #pragma unroll
    for (int ct = 0; ct < 4; ++ct)
      #pragma unroll
      for (int r = 0; r < 4; ++r)
        ap[r * 64 + ct * 16 + l15] = pr[ct][r];

    // PV through lane-ordered per-wave P scratch; V frags from LDS
    f32x4 xa[2];
    { f32x4 z = {0.f, 0.f, 0.f, 0.f}; xa[0] = z; xa[1] = z; }
    #pragma unroll
    for (int ks = 0; ks < 2; ++ks) {
      #pragma unroll
      for (int c = 0; c < 2; ++c)
        #pragma unroll
        for (int r = 0; r < 4; ++r) {
          int col  = c * 16 + l15;
          int kgp  = col >> 3;
          int j    = col & 7;
          int prow = lhi * 4 + r;
          *reinterpret_cast<u16*>(sP + ((kgp * 16 + prow) * 8 + j) * 2) = f2b(pr[ks * 2 + c][r]);
        }
      bf16x8 apf = *reinterpret_cast<const bf16x8*>(sP + lane * 16);
      #pragma unroll
      for (int ctv = 0; ctv < 2; ++ctv) {
        int vrow = h * 32 + ctv * 16 + l15;
        bf16x8 bvf = *reinterpret_cast<const bf16x8*>(sVT + vrow * VROWB + swz(vrow, ks * 64 + lhi * 16));
        xa[ctv] = __builtin_amdgcn_mfma_f32_16x16x32_bf16(apf, bvf, xa[ctv], 0, 0, 0);
      }
    }

    // X -> LDS (swizzled)
    #pragma unroll
    for (int ctv = 0; ctv < 2; ++ctv)
      #pragma unroll
      for (int r = 0; r < 4; ++r) {
        int xrow = rt * 16 + lhi * 4 + r;
        int xcol = h * 32 + ctv * 16 + l15;
        *reinterpret_cast<u16*>(sX + xrow * ROWB + swz(xrow, xcol * 2)) = f2b(xa[ctv][r]);
      }

    aqC = aqN;
  }
  __syncthreads();   // X complete; qh reads done

  // out = X @ Wp + bp (overwrites qh/kh region of x[b], now dead)
  #pragma unroll
  for (int ui = 0; ui < 6; ++ui) {
    int u2 = wave + ui * 4;
    int ct = u2 % 12;
    int rh = u2 / 12;
    const u16* Wt = WT + 3 * 36864 + (ct * 16 + l15) * CEMB + lhi * 8;
    f32x4 oa[2];
    { f32x4 z = {0.f, 0.f, 0.f, 0.f}; oa[0] = z; oa[1] = z; }
    #pragma unroll
    for (int ks = 0; ks < 6; ++ks) {
      bf16x8 bw = *reinterpret_cast<const bf16x8*>(Wt + ks * 32);
      #pragma unroll
      for (int rr = 0; rr < 2; ++rr) {
        int xrow = rh * 32 + rr * 16 + l15;
        bf16x8 ax = *reinterpret_cast<const bf16x8*>(sX + xrow * ROWB + swz(xrow, ks * 64 + lhi * 16));
        oa[rr] = __builtin_amdgcn_mfma_f32_16x16x32_bf16(ax, bw, oa[rr], 0, 0, 0);
      }
    }
    float bias = bp[ct * 16 + l15];
    #pragma unroll
    for (int rr = 0; rr < 2; ++rr)
      #pragma unroll
      for (int r = 0; r < 4; ++r)
        xout[((size_t)b * NTOK + rh * 32 + rr * 16 + lhi * 4 + r) * CEMB + ct * 16 + l15] = oa[rr][r] + bias;
  }
}

extern "C" void kernel_launch(void* const* d_in, const int* in_sizes, int n_in,
                              void* d_out, int out_size, void* d_ws, size_t ws_size,
                              hipStream_t stream) {
  const float* q    = (const float*)d_in[0];
  const float* k    = (const float*)d_in[1];
  const float* v    = (const float*)d_in[2];
  const float* mask = (const float*)d_in[3];
  const float* Wq   = (const float*)d_in[4];
  const float* bq   = (const float*)d_in[5];
  const float* Wk   = (const float*)d_in[6];
  const float* bk   = (const float*)d_in[7];
  const float* Wv   = (const float*)d_in[8];
  const float* bv   = (const float*)d_in[9];
  const float* Wp   = (const float*)d_in[10];
  const float* bp   = (const float*)d_in[11];
  const float* btab = (const float*)d_in[12];
  const int*   ridx = (const int*)d_in[13];

  u16*   WT = (u16*)d_ws;                               // 4 * 36864 bf16
  float* rb = (float*)((char*)d_ws + 4 * 36864 * 2);    // 6*64*64 fp32

  float* xout = (float*)d_out;
  float* attn = xout + (size_t)2048 * NTOK * CEMB;

  prep_kernel<<<672, 256, 0, stream>>>(Wq, Wk, Wv, Wp, btab, ridx, WT, rb);
  proj_kernel<<<6144, 256, 0, stream>>>(q, k, v, bq, bk, bv, WT, xout, attn);
  attn_kernel<<<2048, 256, 0, stream>>>(mask, bp, WT, rb, xout, attn);
}